// Round 2
// baseline (575.684 us; speedup 1.0000x reference)
//
#include <hip/hip_runtime.h>
#include <hip/hip_bf16.h>
#include <cstdint>

typedef unsigned short u16;
typedef unsigned int   u32;
typedef __attribute__((ext_vector_type(8))) short short8;   // 8 bf16 (4 VGPRs) MFMA A/B frag
typedef __attribute__((ext_vector_type(4))) float f32x4;    // MFMA C/D frag / float4 load
typedef __attribute__((ext_vector_type(4))) u32  u32x4;     // 16B staging load
typedef __attribute__((ext_vector_type(2))) u32  u32x2;

#define DEV static __device__ __forceinline__

DEV float bf2f(u16 u){ u32 t = ((u32)u) << 16; float f; __builtin_memcpy(&f, &t, 4); return f; }
DEV u16 f2bf(float f){ u32 t; __builtin_memcpy(&t, &f, 4); return (u16)((t + 0x7fffu + ((t >> 16) & 1u)) >> 16); }

// ---------------------------------------------------------------- dtype probe
// Even-indexed u16s of a genuine bf16 N(0,1) tensor have exponents in ~[0x60,0x82].
// If the tensor is really f32, even u16s are mantissa low-halves: ~75% have wild
// exponents. Count over 1024 samples; >128 wild => f32 mode.
__global__ __launch_bounds__(256) void detect_mode(const u16* __restrict__ x, int* __restrict__ mode)
{
    __shared__ int red[4];
    const int tid = threadIdx.x;
    int crazy = 0;
    for (int i = tid; i < 1024; i += 256) {
        u16 v = x[2 * i];
        int e = (v >> 7) & 0xFF;
        if (e >= 0x9F || (e > 0 && e <= 0x5F)) crazy++;
    }
    #pragma unroll
    for (int off = 1; off < 64; off <<= 1) crazy += __shfl_xor(crazy, off, 64);
    if ((tid & 63) == 0) red[tid >> 6] = crazy;
    __syncthreads();
    if (tid == 0) *mode = (red[0] + red[1] + red[2] + red[3] > 128) ? 1 : 0;
}

// ---------------------------------------------------------------- canonicalize params to bf16 in ws
struct SrcPtrs { const void* p[13]; };

__global__ __launch_bounds__(256) void convert_params(SrcPtrs sp, u16* __restrict__ ws,
                                                      const int* __restrict__ mode)
{
    static const int sizes[13] = {1024,1024,64,64,64,64,1048576,1024,1048576,1024,1048576,1024,1048576};
    static const int offs[13]  = {
        37748736 + 0,     // norm_w
        37748736 + 1024,  // norm_b
        37748736 + 5120,  // qn_w
        37748736 + 5184,  // qn_b
        37748736 + 5248,  // kn_w
        37748736 + 5312,  // kn_b
        33554432,         // Wq
        37748736 + 2048,  // bq
        34603008,         // Wk
        37748736 + 3072,  // bk
        35651584,         // Wv
        37748736 + 4096,  // bv
        36700160          // Wo
    };
    const int t = blockIdx.y;
    const int i = blockIdx.x * 256 + threadIdx.x;
    if (i >= sizes[t]) return;
    const bool f32m = (*mode != 0);
    ws[offs[t] + i] = f32m ? f2bf(((const float*)sp.p[t])[i]) : ((const u16*)sp.p[t])[i];
}

// ---------------------------------------------------------------- LayerNorm over D=1024 (dual-mode x)
__global__ __launch_bounds__(256) void ln_kernel(const void* __restrict__ x,
                                                 const u16* __restrict__ w,
                                                 const u16* __restrict__ b,
                                                 u16* __restrict__ xn,
                                                 const int* __restrict__ mode)
{
    const int row = blockIdx.x;          // 0..8191
    const int tid = threadIdx.x;
    const int wv = tid >> 6, lane = tid & 63;

    float v0, v1, v2, v3;
    if (*mode) {
        f32x4 r = *((const f32x4*)((const float*)x + row * 1024) + tid);
        v0 = r[0]; v1 = r[1]; v2 = r[2]; v3 = r[3];
    } else {
        u32x2 raw = *(const u32x2*)((const u16*)x + row * 1024 + tid * 4);
        v0 = bf2f((u16)(raw.x & 0xffff)); v1 = bf2f((u16)(raw.x >> 16));
        v2 = bf2f((u16)(raw.y & 0xffff)); v3 = bf2f((u16)(raw.y >> 16));
    }
    float s  = v0 + v1 + v2 + v3;
    float sq = v0*v0 + v1*v1 + v2*v2 + v3*v3;
    #pragma unroll
    for (int off = 1; off < 64; off <<= 1) {
        s  += __shfl_xor(s,  off, 64);
        sq += __shfl_xor(sq, off, 64);
    }
    __shared__ float red[8];
    if (lane == 0) { red[wv] = s; red[4 + wv] = sq; }
    __syncthreads();
    float ts = red[0] + red[1] + red[2] + red[3];
    float tq = red[4] + red[5] + red[6] + red[7];
    float mean = ts * (1.0f / 1024.0f);
    float var  = tq * (1.0f / 1024.0f) - mean * mean;
    float rs   = rsqrtf(var + 1e-5f);

    float y0 = (v0 - mean) * rs * bf2f(w[tid*4+0]) + bf2f(b[tid*4+0]);
    float y1 = (v1 - mean) * rs * bf2f(w[tid*4+1]) + bf2f(b[tid*4+1]);
    float y2 = (v2 - mean) * rs * bf2f(w[tid*4+2]) + bf2f(b[tid*4+2]);
    float y3 = (v3 - mean) * rs * bf2f(w[tid*4+3]) + bf2f(b[tid*4+3]);
    u32x2 out;
    out.x = (u32)f2bf(y0) | ((u32)f2bf(y1) << 16);
    out.y = (u32)f2bf(y2) | ((u32)f2bf(y3) << 16);
    *(u32x2*)(xn + row * 1024 + tid * 4) = out;
}

// ---------------------------------------------------------------- GEMM: C[M][N] = A[M][K] @ W[N][K]^T + bias
// 64x64 tile, 4 waves (2x2), each wave 32x32 via 2x2 mfma_16x16x32_bf16.
// LDS stride 72 elems (144B): 16B-aligned rows, <=2-way bank conflicts (free).
// Output dtype: bf16, or f32 when (applyMode && *mode).
__global__ __launch_bounds__(256) void gemm_bt(const u16* __restrict__ A,
                                               const u16* __restrict__ W,
                                               const u16* __restrict__ bias,
                                               void* __restrict__ C,
                                               const int* __restrict__ mode, int applyMode,
                                               int M, int N, int K)
{
    __shared__ u16 As[64 * 72];
    __shared__ u16 Ws[64 * 72];
    const int tid = threadIdx.x;
    const int m0 = blockIdx.x * 64, n0 = blockIdx.y * 64;
    const int wv = tid >> 6, lane = tid & 63, quad = lane >> 4, l16 = lane & 15;
    const int wm = wv & 1, wn = wv >> 1;

    f32x4 acc00 = {0,0,0,0}, acc01 = {0,0,0,0}, acc10 = {0,0,0,0}, acc11 = {0,0,0,0};

    const int lrow = tid >> 2, lcol = (tid & 3) * 16;
    const u16* Ap = A + (m0 + lrow) * K + lcol;
    const u16* Wp = W + (n0 + lrow) * K + lcol;
    u16* Asp = &As[lrow * 72 + lcol];
    u16* Wsp = &Ws[lrow * 72 + lcol];

    for (int k0 = 0; k0 < K; k0 += 64) {
        u32x4 a0 = *(const u32x4*)(Ap + k0), a1 = *(const u32x4*)(Ap + k0 + 8);
        u32x4 w0 = *(const u32x4*)(Wp + k0), w1 = *(const u32x4*)(Wp + k0 + 8);
        *(u32x4*)Asp = a0; *(u32x4*)(Asp + 8) = a1;
        *(u32x4*)Wsp = w0; *(u32x4*)(Wsp + 8) = w1;
        __syncthreads();
        #pragma unroll
        for (int ks = 0; ks < 64; ks += 32) {
            short8 af0 = *(const short8*)&As[(wm*32      + l16) * 72 + ks + quad*8];
            short8 af1 = *(const short8*)&As[(wm*32 + 16 + l16) * 72 + ks + quad*8];
            short8 bf0 = *(const short8*)&Ws[(wn*32      + l16) * 72 + ks + quad*8];
            short8 bf1 = *(const short8*)&Ws[(wn*32 + 16 + l16) * 72 + ks + quad*8];
            acc00 = __builtin_amdgcn_mfma_f32_16x16x32_bf16(af0, bf0, acc00, 0, 0, 0);
            acc01 = __builtin_amdgcn_mfma_f32_16x16x32_bf16(af0, bf1, acc01, 0, 0, 0);
            acc10 = __builtin_amdgcn_mfma_f32_16x16x32_bf16(af1, bf0, acc10, 0, 0, 0);
            acc11 = __builtin_amdgcn_mfma_f32_16x16x32_bf16(af1, bf1, acc11, 0, 0, 0);
        }
        __syncthreads();
    }

    const bool f32out = applyMode && (*mode != 0);
    f32x4 accs[2][2] = {{acc00, acc01}, {acc10, acc11}};
    #pragma unroll
    for (int sn = 0; sn < 2; sn++) {
        const int col = n0 + wn*32 + sn*16 + l16;
        const float bv = bias ? bf2f(bias[col]) : 0.0f;
        #pragma unroll
        for (int sm = 0; sm < 2; sm++) {
            #pragma unroll
            for (int r = 0; r < 4; r++) {
                const int row = m0 + wm*32 + sm*16 + quad*4 + r;
                const float val = accs[sm][sn][r] + bv;
                if (f32out) ((float*)C)[row * N + col] = val;
                else        ((u16*)C)[row * N + col]  = f2bf(val);
            }
        }
    }
}

// ---------------------------------------------------------------- per-head LN over DH=64 (+q scale), in place
__global__ __launch_bounds__(256) void headln(u16* __restrict__ q, u16* __restrict__ k,
                                              const u16* __restrict__ qw, const u16* __restrict__ qb,
                                              const u16* __restrict__ kw, const u16* __restrict__ kb)
{
    const int isK = blockIdx.y;
    u16* buf = isK ? k : q;
    const u16* w = isK ? kw : qw;
    const u16* b = isK ? kb : qb;
    const float scale = isK ? 1.0f : 0.125f;   // DH^-0.5 = 1/8 on q
    const int wv = threadIdx.x >> 6, lane = threadIdx.x & 63;
    const int r = blockIdx.x * 4 + wv;         // head-row 0..131071; addr = r*64+lane (coalesced)
    u16* p = buf + r * 64;
    float v = bf2f(p[lane]);
    float s = v, sq = v * v;
    #pragma unroll
    for (int off = 1; off < 64; off <<= 1) {
        s  += __shfl_xor(s,  off, 64);
        sq += __shfl_xor(sq, off, 64);
    }
    float mean = s * (1.0f / 64.0f);
    float var  = sq * (1.0f / 64.0f) - mean * mean;
    float rs   = rsqrtf(var + 1e-5f);
    float y = ((v - mean) * rs * bf2f(w[lane]) + bf2f(b[lane])) * scale;
    p[lane] = f2bf(y);
}

// ---------------------------------------------------------------- flash attention
// grid (32, 64): x = Q-tile of 64 rows, y = (b*16+h). 4 waves, wave handles 16 Q rows.
// S^T = K_tile * Q^T via mfma (C-layout: row=j=quad*4+r, col=i=lane&15) -> softmax stats
// indexed by i=lane&15 -> P round-trips LDS into A-layout -> PV via mfma vs LDS-transposed V.
// No infinities anywhere: mask = -1e9, m_run init = -1e8; exp underflow gives exact 0
// for masked keys (|S| <= ~512 << 1e8).
__global__ __launch_bounds__(256) void attn(const u16* __restrict__ q, const u16* __restrict__ k,
                                            const u16* __restrict__ v, const int* __restrict__ mask,
                                            u16* __restrict__ ctx)
{
    __shared__ float maskf[2048];
    __shared__ u16 Vt[64 * 40];      // [dh][j] stride 40 (2-way conflicts only)
    __shared__ u16 Ps[4 * 16 * 40];  // per wave [i][j] stride 40

    const int bh = blockIdx.y, b = bh >> 4, h = bh & 15;
    const int i0 = blockIdx.x * 64;
    const int tid = threadIdx.x, wv = tid >> 6, lane = tid & 63, quad = lane >> 4, l16 = lane & 15;

    for (int idx = tid; idx < 2048; idx += 256)
        maskf[idx] = mask[b * 2048 + idx] ? 0.0f : -1e9f;

    const u16* qbase = q + (b * 2048) * 1024 + h * 64;
    const u16* kbase = k + (b * 2048) * 1024 + h * 64;
    const u16* vbase = v + (b * 2048) * 1024 + h * 64;

    const int iw = i0 + wv * 16 + l16;   // B-operand: n=lane&15 -> query row
    short8 qf0 = *(const short8*)(qbase + iw * 1024 +      quad * 8);
    short8 qf1 = *(const short8*)(qbase + iw * 1024 + 32 + quad * 8);

    f32x4 O[4] = {{0,0,0,0},{0,0,0,0},{0,0,0,0},{0,0,0,0}};
    float m_run = -1e8f, l_run = 0.0f;

    const int vj = tid >> 3, vdh = (tid & 7) * 8;   // V staging: thread -> (j, dh-chunk)
    const int pbase = wv * 640 + l16 * 40;

    __syncthreads();   // maskf ready

    for (int j0 = 0; j0 < 2048; j0 += 32) {
        // stage V^T tile [64 dh][32 j]
        u32x4 vraw = *(const u32x4*)(vbase + (j0 + vj) * 1024 + vdh);
        const u16* pv = (const u16*)&vraw;
        #pragma unroll
        for (int e = 0; e < 8; e++) Vt[(vdh + e) * 40 + vj] = pv[e];

        // S^T for two 16-wide j subtiles
        f32x4 sfr[2];
        #pragma unroll
        for (int sub = 0; sub < 2; sub++) {
            const int jt = j0 + sub * 16;
            short8 kf0 = *(const short8*)(kbase + (jt + l16) * 1024 +      quad * 8);
            short8 kf1 = *(const short8*)(kbase + (jt + l16) * 1024 + 32 + quad * 8);
            f32x4 sz = {0,0,0,0};
            sz = __builtin_amdgcn_mfma_f32_16x16x32_bf16(kf0, qf0, sz, 0, 0, 0);
            sz = __builtin_amdgcn_mfma_f32_16x16x32_bf16(kf1, qf1, sz, 0, 0, 0);
            sfr[sub] = sz;
        }

        // online softmax (row stats live at i = lane&15, replicated across quads)
        float p[2][4], mt = -1e30f;
        #pragma unroll
        for (int sub = 0; sub < 2; sub++)
            #pragma unroll
            for (int r = 0; r < 4; r++) {
                float sv = sfr[sub][r] + maskf[j0 + sub * 16 + quad * 4 + r];
                p[sub][r] = sv;
                mt = fmaxf(mt, sv);
            }
        mt = fmaxf(mt, __shfl_xor(mt, 16, 64));
        mt = fmaxf(mt, __shfl_xor(mt, 32, 64));
        float mnew  = fmaxf(m_run, mt);
        float alpha = __expf(m_run - mnew);
        float rsum = 0.0f;
        #pragma unroll
        for (int sub = 0; sub < 2; sub++)
            #pragma unroll
            for (int r = 0; r < 4; r++) {
                float e = __expf(p[sub][r] - mnew);
                p[sub][r] = e;
                rsum += e;
            }
        rsum += __shfl_xor(rsum, 16, 64);
        rsum += __shfl_xor(rsum, 32, 64);
        l_run = l_run * alpha + rsum;
        m_run = mnew;

        // rescale O: O rows are i = quad*4+r (C-layout) -> fetch alpha(i) by shuffle
        float ar[4];
        #pragma unroll
        for (int r = 0; r < 4; r++) ar[r] = __shfl(alpha, quad * 4 + r, 64);
        #pragma unroll
        for (int dht = 0; dht < 4; dht++)
            #pragma unroll
            for (int r = 0; r < 4; r++) O[dht][r] *= ar[r];

        // P -> LDS in A-layout [i = lane&15][j 0..31]
        #pragma unroll
        for (int sub = 0; sub < 2; sub++) {
            u32 w0 = (u32)f2bf(p[sub][0]) | ((u32)f2bf(p[sub][1]) << 16);
            u32 w1 = (u32)f2bf(p[sub][2]) | ((u32)f2bf(p[sub][3]) << 16);
            *(u32*)&Ps[pbase + sub * 16 + quad * 4]     = w0;
            *(u32*)&Ps[pbase + sub * 16 + quad * 4 + 2] = w1;
        }
        __syncthreads();   // Vt + P visible

        short8 pf = *(const short8*)&Ps[pbase + quad * 8];
        #pragma unroll
        for (int dht = 0; dht < 4; dht++) {
            short8 vf = *(const short8*)&Vt[(dht * 16 + l16) * 40 + quad * 8];
            O[dht] = __builtin_amdgcn_mfma_f32_16x16x32_bf16(pf, vf, O[dht], 0, 0, 0);
        }
        __syncthreads();   // done reading before next stage overwrites
    }

    float lr[4];
    #pragma unroll
    for (int r = 0; r < 4; r++) lr[r] = __shfl(l_run, quad * 4 + r, 64);
    u16* cbase = ctx + (b * 2048) * 1024 + h * 64;
    #pragma unroll
    for (int r = 0; r < 4; r++) {
        const int irow = i0 + wv * 16 + quad * 4 + r;
        const float inv = lr[r] > 0.0f ? 1.0f / lr[r] : 0.0f;
        #pragma unroll
        for (int dht = 0; dht < 4; dht++)
            cbase[irow * 1024 + dht * 16 + l16] = f2bf(O[dht][r] * inv);
    }
}

// ----------------------------------------------------------------
extern "C" void kernel_launch(void* const* d_in, const int* in_sizes, int n_in,
                              void* d_out, int out_size, void* d_ws, size_t ws_size,
                              hipStream_t stream)
{
    const int* mask = (const int*)d_in[1];

    u16* ws = (u16*)d_ws;
    u16* xn  = ws;                      // [0, 8M) elems
    u16* qb  = ws + 8388608;            // [8M, 16M)
    u16* kb  = ws + 16777216;           // [16M, 24M)
    u16* vb  = ws + 25165824;           // [24M, 32M)
    u16* ctx = xn;                      // xn dead after V-GEMM; reuse
    u16* cW  = ws + 33554432;           // Wq, Wk, Wv, Wo (1M each)
    u16* cV  = ws + 37748736;           // vectors
    int* mode = (int*)(ws + 37754176);  // dtype flag

    detect_mode<<<dim3(1), dim3(256), 0, stream>>>((const u16*)d_in[0], mode);

    SrcPtrs sp;
    for (int i = 0; i < 13; i++) sp.p[i] = d_in[i + 2];
    convert_params<<<dim3(4096, 13), dim3(256), 0, stream>>>(sp, ws, mode);

    ln_kernel<<<dim3(8192), dim3(256), 0, stream>>>(d_in[0], cV + 0, cV + 1024, xn, mode);

    gemm_bt<<<dim3(128, 16), dim3(256), 0, stream>>>(xn, cW + 0,       cV + 2048, qb, mode, 0, 8192, 1024, 1024);
    gemm_bt<<<dim3(128, 16), dim3(256), 0, stream>>>(xn, cW + 1048576, cV + 3072, kb, mode, 0, 8192, 1024, 1024);
    gemm_bt<<<dim3(128, 16), dim3(256), 0, stream>>>(xn, cW + 2097152, cV + 4096, vb, mode, 0, 8192, 1024, 1024);

    headln<<<dim3(32768, 2), dim3(256), 0, stream>>>(qb, kb, cV + 5120, cV + 5184, cV + 5248, cV + 5312);

    attn<<<dim3(32, 64), dim3(256), 0, stream>>>(qb, kb, vb, mask, ctx);

    gemm_bt<<<dim3(128, 16), dim3(256), 0, stream>>>(ctx, cW + 3145728, nullptr, d_out, mode, 1, 8192, 1024, 1024);
}